// Round 21
// baseline (97.099 us; speedup 1.0000x reference)
//
#include <hip/hip_runtime.h>
#include <cstddef>

namespace {
constexpr int cB = 64, cN = 34, cF = 16, cT = 96, cK = 3, cO = 64;
constexpr int LPS = 40;   // u16 pitch (80B rows); cols 34..39 zero k-pad
constexpr int T4 = cT / 4;
constexpr float cEPS = 1e-8f;

typedef __attribute__((ext_vector_type(8))) _Float16 f16x8;
typedef __attribute__((ext_vector_type(8))) short   s16x8;
typedef __attribute__((ext_vector_type(4))) float   f32x4;
typedef __attribute__((ext_vector_type(4))) unsigned u32x4;

__device__ inline unsigned short f2h(float v) {
    _Float16 h = (_Float16)v;
    return __builtin_bit_cast(unsigned short, h);
}
__device__ inline float h2f(unsigned short u) {
    return (float)__builtin_bit_cast(_Float16, u);
}

// H staging dword address, interleaved inside d_out. s = tt*40 + c, c < 40.
// Slots of tile (b,t4) live only in out[:, o<40, 4*t4..4*t4+3] — exactly the
// region block (b,t4) of proj_k later overwrites: race-free across blocks.
// Injective ONLY for c<40 (r20 bug: c>=40 aliases other tt / unwritten slots
// whose replay contents can be fp16-NaN patterns -> NaN*0=NaN).
// Key property: for c = 4q..4q+3 (same tt), the 4 dwords are CONSECUTIVE and
// 16B-aligned in memory (o fixed, t cycles 4t4..4t4+3) -> float4-loadable.
__device__ inline size_t hidx(int b, int t4, int j, int tt, int c) {
    int s = tt * 40 + c;
    return (((size_t)b * cN + j) * cO + (s >> 2)) * cT + 4 * t4 + (s & 3);
}
}

// ---------------- softmax over axis=2 (i) of st_attention (B,K,N,N) ----------------
__global__ __launch_bounds__(256) void att_softmax_k(const float* __restrict__ st,
                                                     float* __restrict__ att) {
    int idx = blockIdx.x * blockDim.x + threadIdx.x;
    if (idx >= cB * cK * cN) return;
    int j = idx % cN;
    int bk = idx / cN;
    const float* base = st + (size_t)bk * cN * cN + j;
    float v[cN];
    float m = -3.402823466e38f;
#pragma unroll
    for (int i = 0; i < cN; ++i) { v[i] = base[(size_t)i * cN]; m = fmaxf(m, v[i]); }
    float s = 0.f;
#pragma unroll
    for (int i = 0; i < cN; ++i) { v[i] = __expf(v[i] - m); s += v[i]; }
    float inv = 1.f / s;
    float* ob = att + (size_t)bk * cN * cN + j;
#pragma unroll
    for (int i = 0; i < cN; ++i) ob[(size_t)i * cN] = v[i] * inv;
}

// ---------------- kernel A: one block per (b,t); H(34x80 fp16) -> staged in out ----------------
// r15 structure (proven 85.3us): A gets its own buffer (s_Abuf) which later
// becomes the M2T/M4T home -> no stash, no pad re-zeroing in P3, b5 deleted
// (P5 writes dead A space right after P4). 5 interior barriers.
// r17 lesson: do NOT wrap this body in a t-loop — the loop demotes the MFMA
// accumulators to scratch (30x FETCH/WRITE explosion).
__global__ __launch_bounds__(256, 8) void cheb_h_k(
    const float* __restrict__ x,      // (B,N,F,T)
    const float* __restrict__ att,    // (B,K,N,N) softmaxed
    const float* __restrict__ pos,    // (N,2)
    const float* __restrict__ dist,   // (N,N)
    unsigned* __restrict__ Hst)       // = (unsigned*)out, staging slots
{
    // Declaration order matters (A-frag row-overrun reads up to ~1120B past an
    // array must land in allocated LDS): Abuf(w3 M4T overruns into L1), L2->M1T,
    // M1T->M3T, M3T->gsT (1280B >= 1118B needed).
    __shared__ __align__(16) unsigned short s_Abuf[2 * cN * LPS]; // A fp32 ovl; M2T rows0..33, M4T rows34..67
    __shared__ __align__(16) unsigned short s_L1[cN * LPS];   // L1 (pads stay init-zero)
    __shared__ __align__(16) unsigned short s_L2[cN * LPS];   // L2
    __shared__ __align__(16) unsigned short s_M1T[cN * LPS];  // att1 .* L1, transposed
    __shared__ __align__(16) unsigned short s_M3T[cN * LPS];  // att1 .* L2, transposed
    __shared__ __align__(16) unsigned short s_gsT[cF * LPS];  // gs^T fp16 (single-writer)
    __shared__ float s_d0[cN], s_v1[cN], s_v2[cN], s_p1[cN], s_p2[cN], s_di1[cN], s_di2[cN];

    const int tid = threadIdx.x;
    const int lane = tid & 63;
    const int w = tid >> 6;
    const int lr = lane & 15;
    const int lg = lane >> 4;
    const int kb8 = lg * 8;

    // XCD swizzle (grid 6144, %8==0 -> bijective)
    const unsigned g = blockIdx.x;
    const unsigned lin = (g & 7u) * (cB * cT / 8) + (g >> 3);
    const int b = lin / cT, t = lin % cT;
    const int t4 = t >> 2, tt = t & 3;

    // idx -> (i,j) decomposition, computed once, reused in P2/P3
    int ii[5], jj[5];
#pragma unroll
    for (int e = 0; e < 5; ++e) {
        int idx = tid + 256 * e;
        ii[e] = idx / cN;
        jj[e] = idx - ii[e] * cN;
    }

    // ---- init: zero L/MT arrays (f32x4); stage p-hat/d0/v'/gsT. Abuf NOT zeroed
    //      (A fp32 overlays it; fp16 pads handled in P5). ----
    {
        f32x4 z = (f32x4){0.f, 0.f, 0.f, 0.f};
        for (int i2 = tid; i2 < cN * LPS / 8; i2 += 256) {
            ((f32x4*)s_L1)[i2] = z; ((f32x4*)s_L2)[i2] = z;
            ((f32x4*)s_M1T)[i2] = z; ((f32x4*)s_M3T)[i2] = z;
        }
    }
    if (tid < cN) {
        float px = pos[2 * tid], py = pos[2 * tid + 1];
        float pn = sqrtf(px * px + py * py);
        float r = 1.f / fmaxf(pn, cEPS);
        s_p1[tid] = px * r; s_p2[tid] = py * r;
        s_d0[tid] = att[((size_t)b * cK) * cN * cN + tid * cN + tid];
    } else if (tid >= 64 && tid < 64 + cN) {
        int n = tid - 64;
        float x1 = x[(((size_t)b * cN + n) * cF + 1) * cT + t];
        float x2 = x[(((size_t)b * cN + n) * cF + 2) * cT + t];
        float vn = sqrtf(x1 * x1 + x2 * x2);
        float s = vn / fmaxf(vn, cEPS);
        s_v1[n] = x1 * s; s_v2[n] = x2 * s;
    }
    // single-writer gsT fill: data for n<34, zero pads for n>=34 (race lesson, r8)
    for (int idx = tid; idx < cF * LPS; idx += 256) {
        int f = idx / LPS, n = idx - f * LPS;
        unsigned short v = 0;
        if (n < cN) v = f2h(x[(((size_t)b * cN + n) * cF + f) * cT + t]);
        s_gsT[idx] = v;
    }
    __syncthreads();  // b1

    // ---- P2: adjacency A fp32 (compact 34x34) into s_Abuf ----
    float* Af = (float*)s_Abuf;
#pragma unroll
    for (int e = 0; e < 5; ++e) {
        int idx = tid + 256 * e;
        if (idx < cN * cN) {
            int i = ii[e], m = jj[e];
            float dot = s_v1[i] * s_p1[m] + s_v2[i] * s_p2[m];
            Af[idx] = __fdividef(fmaxf(dot, 0.f), dist[idx]);
        }
    }
    __syncthreads();  // b2

    // ---- P2b: degrees, 2 threads per sum (17 elems each + shfl combine) ----
    if (tid < 136) {
        int s = tid >> 1, half = tid & 1;
        float acc = 0.f;
        if (s < cN) {
            const float* row = Af + s * cN + half * 17;
#pragma unroll
            for (int m = 0; m < 17; ++m) acc += row[m];
        } else {
            int j = s - cN;
            const float* col = Af + half * 17 * cN + j;
#pragma unroll
            for (int i = 0; i < 17; ++i) acc += col[i * cN];
        }
        float tot = acc + __shfl_xor(acc, 1, 64);
        if (half == 0) {
            float d = (tot > 0.f) ? rsqrtf(fmaxf(tot, 1e-12f)) : 0.f;
            if (s < cN) s_di1[s] = d; else s_di2[s - cN] = d;
        }
    }
    __syncthreads();  // b3 (di done; A stays readable — no stash needed)

    // ---- P3: L1/L2 fp16 (pads untouched = init zeros), M1T/M3T = att1.*L^T ----
    const float* att1 = att + ((size_t)b * cK + 1) * cN * cN;
    const float* att2 = att + ((size_t)b * cK + 2) * cN * cN;
#pragma unroll
    for (int e = 0; e < 5; ++e) {
        int idx = tid + 256 * e;
        if (idx < cN * cN) {
            int i = ii[e], j = jj[e];
            float diag = (i == j) ? 1.f : 0.f;
            float aij = Af[idx];
            float aji = Af[j * cN + i];
            float l1 = diag - s_di1[i] * aij * s_di1[j];
            float l2 = diag - s_di2[i] * aji * s_di2[j];
            int rm = i * LPS + j, tm = j * LPS + i;
            s_L1[rm] = f2h(l1);
            s_L2[rm] = f2h(l2);
            float a1 = att1[idx];
            s_M1T[tm] = f2h(a1 * l1);
            s_M3T[tm] = f2h(a1 * l2);
        }
    }
    __syncthreads();  // b4 (A reads done; L/MT ready)

    // ---- P4: C = L@L fp16 MFMA; ks1: A at fixed col 32 (all lanes), B zeroed
    //      except lg==0 k=32,33 -> lg>0 k-slices contribute A*0 = 0 ----
    const unsigned short* Ah = (w < 2) ? s_L1 : s_L2;
    const int nnt = (w & 1) ? 1 : 2;
    const int ntb0 = (w & 1) ? 32 : 0;
    f32x4 cd0[3], cd1[3];
#pragma unroll
    for (int mt = 0; mt < 3; ++mt) {
        cd0[mt] = (f32x4){0.f, 0.f, 0.f, 0.f};
        cd1[mt] = (f32x4){0.f, 0.f, 0.f, 0.f};
    }
#pragma unroll
    for (int ks = 0; ks < 2; ++ks) {
        f16x8 fah[3];
#pragma unroll
        for (int mt = 0; mt < 3; ++mt) {
            int off = (ks == 0) ? kb8 : 32;
            fah[mt] = *(const f16x8*)&Ah[(mt * 16 + lr) * LPS + off];
        }
#pragma unroll
        for (int un = 0; un < 2; ++un) {
            if (un == 1 && nnt < 2) break;
            int col = ntb0 + un * 16 + lr;
            s16x8 fbb;
            if (ks == 0) {
                // kk = kb8+e2 <= 31 < 34: always valid
#pragma unroll
                for (int e2 = 0; e2 < 8; ++e2)
                    fbb[e2] = (short)Ah[(kb8 + e2) * LPS + col];
            } else {
                // kk = 32+kb8+e2: valid only lg==0 && e2<2; rest zero
#pragma unroll
                for (int e2 = 0; e2 < 8; ++e2) fbb[e2] = 0;
                if (lg == 0) {
                    fbb[0] = (short)Ah[32 * LPS + col];
                    fbb[1] = (short)Ah[33 * LPS + col];
                }
            }
            f16x8 fb = __builtin_bit_cast(f16x8, fbb);
#pragma unroll
            for (int mt = 0; mt < 3; ++mt) {
                f32x4 acc = un ? cd1[mt] : cd0[mt];
                acc = __builtin_amdgcn_mfma_f32_16x16x32_f16(fah[mt], fb, acc, 0, 0, 0);
                if (un) cd1[mt] = acc; else cd0[mt] = acc;
            }
        }
    }
    // NO barrier: P5 writes s_Abuf (dead A space), not the L arrays other
    // waves may still be reading in P4. Register-fed from this wave's cd.

    // ---- P5: M2T = att2 .* (2C1 - I) -> Abuf rows 0..33; M4T -> rows 34..67.
    //      Also zero fp16 pad cols 34..39 (A-garbage could be NaN-as-fp16). ----
    {
        unsigned* Md32 = (unsigned*)s_Abuf + ((w < 2) ? 0 : (cN * LPS / 2));
#pragma unroll
        for (int un = 0; un < 2; ++un) {
            if (un == 1 && nnt < 2) break;
            int jb = ntb0 + un * 16 + lr;
            if (jb < cN) {
#pragma unroll
                for (int mt = 0; mt < 3; ++mt) {
#pragma unroll
                    for (int h = 0; h < 2; ++h) {
                        int ia = mt * 16 + lg * 4 + 2 * h;   // even; ia+1 <= 33 when ia < 34
                        if (ia < cN) {
                            float dva = h ? (un ? cd1[mt][2] : cd0[mt][2])
                                          : (un ? cd1[mt][0] : cd0[mt][0]);
                            float dvb = h ? (un ? cd1[mt][3] : cd0[mt][3])
                                          : (un ? cd1[mt][1] : cd0[mt][1]);
                            float cva = 2.f * dva - ((ia == jb) ? 1.f : 0.f);
                            float cvb = 2.f * dvb - ((ia + 1 == jb) ? 1.f : 0.f);
                            unsigned lo = f2h(att2[ia * cN + jb] * cva);
                            unsigned hi = f2h(att2[(ia + 1) * cN + jb] * cvb);
                            Md32[jb * (LPS / 2) + (ia >> 1)] = lo | (hi << 16);
                        }
                    }
                }
                // pad cols 34..39 of row jb -> true zero (3 dwords)
                Md32[jb * (LPS / 2) + 17] = 0u;
                Md32[jb * (LPS / 2) + 18] = 0u;
                Md32[jb * (LPS / 2) + 19] = 0u;
            }
        }
    }
    __syncthreads();  // b5 (M2T/M4T ready for cross-wave P6 reads)

    // ---- P6: H_p = M_p^T @ gs (wave w -> p=w+1); direct global stores ----
    {
        const unsigned short* Ap = (w == 0) ? s_M1T : (w == 1) ? s_Abuf
                                 : (w == 2) ? s_M3T : (s_Abuf + cN * LPS);
        f32x4 hd[3];
#pragma unroll
        for (int mt = 0; mt < 3; ++mt) hd[mt] = (f32x4){0.f, 0.f, 0.f, 0.f};
#pragma unroll
        for (int ks = 0; ks < 2; ++ks) {
            f16x8 fb;
            if (ks == 0) {
                fb = *(const f16x8*)&s_gsT[lr * LPS + kb8];
            } else {
                // B zero except lg==0 (k=32,33 + zero pads 34..39)
                s16x8 z = {0, 0, 0, 0, 0, 0, 0, 0};
                if (lg == 0) z = *(const s16x8*)&s_gsT[lr * LPS + 32];
                fb = __builtin_bit_cast(f16x8, z);
            }
#pragma unroll
            for (int mt = 0; mt < 3; ++mt) {
                int off = (ks == 0) ? kb8 : 32;   // ks1: all lanes col 32 (B zeroed)
                f16x8 fa = *(const f16x8*)&Ap[(mt * 16 + lr) * LPS + off];
                hd[mt] = __builtin_amdgcn_mfma_f32_16x16x32_f16(fa, fb, hd[mt], 0, 0, 0);
            }
        }
        // p0 diag block (H cols 0..15 = dwords 0..7), all threads
        for (int idx = tid; idx < cN * 8; idx += 256) {
            int j = idx >> 3, c = idx & 7;
            float d = s_d0[j];
            unsigned lo = f2h(d * h2f(s_gsT[(2 * c) * LPS + j]));
            unsigned hi = f2h(d * h2f(s_gsT[(2 * c + 1) * LPS + j]));
            Hst[hidx(b, t4, j, tt, c)] = lo | (hi << 16);
        }
        // pack lane pairs (cols pc+lr, pc+lr^1) -> one dword; split stores by r
        const int pc = 16 * (w + 1);
        const int cdw = (pc >> 1) + (lr >> 1);
#pragma unroll
        for (int mt = 0; mt < 3; ++mt) {
#pragma unroll
            for (int r = 0; r < 4; ++r) {
                int j = mt * 16 + lg * 4 + r;
                unsigned mine = (unsigned)f2h(hd[mt][r]);
                unsigned other = __shfl_xor(mine, 1, 64);
                unsigned dword = (lr & 1) ? ((other & 0xffffu) | (mine << 16))
                                          : (mine | (other << 16));
                bool mystore = ((lr & 1) == 0) ? (r < 2) : (r >= 2);
                if (mystore && j < cN)
                    Hst[hidx(b, t4, j, tt, cdw)] = dword;
            }
        }
    }
}

// ---------------- kernel B: one block per (b,t4); out = relu(H @ Thcat) ----------------
// LDS-free: each MFMA A-fragment is 4 consecutive 16B-aligned staging dwords
// (hidx property, c<40) -> direct float4 global loads. Fragments covering
// k-cols >= 80 (s==2 && lg>=2) are ZEROED instead of loaded: their B-entries
// are zero anyway, and loading would touch c>=40 slots that alias other tt's
// data or unwritten out bytes (r20 replay-nondeterminism bug: stale float32
// low halfwords can be fp16 NaN -> NaN*0=NaN). Within the block, a barrier
// separates all waves' staging loads from any wave's output stores (r19 bug).
__global__ __launch_bounds__(256, 4) void proj_k(
    const unsigned* __restrict__ Hst,   // staging view of out
    const float* __restrict__ Th,       // (K,F,O)
    const float* __restrict__ ThL,      // (K,F,O)
    float* __restrict__ out)            // (B,N,O,T)
{
    const int tid = threadIdx.x;
    const int lane = tid & 63;
    const int w = tid >> 6;
    const int lr = lane & 15;
    const int lg = lane >> 4;
    const int kb8 = lg * 8;
    const int ocol = w * 16 + lr;

    const unsigned g = blockIdx.x;
    const unsigned lin = (g & 7u) * (cB * T4 / 8) + (g >> 3);
    const int b = lin / T4, t4 = lin % T4;
    const int t0 = t4 * 4;

    // A-fragment row for (mt,lr): m-row = mt*16+lr = 4*j + tt
    const int jlr = lr >> 2, ttl = lr & 3;

    // ---- Theta B-fragments fp16 (c = p*16+f; p0 = Th0+ThL0 merged) ----
    f16x8 bfr[3];
#pragma unroll
    for (int s = 0; s < 3; ++s) {
#pragma unroll
        for (int j = 0; j < 8; ++j) {
            int cc = 32 * s + kb8 + j;
            float v = 0.f;
            if (cc < 80) {
                int p = cc >> 4, f = cc & 15;
                if (p == 0)      v = Th[f * cO + ocol] + ThL[f * cO + ocol];
                else if (p == 1) v = Th[(cF + f) * cO + ocol];
                else if (p == 2) v = Th[(2 * cF + f) * cO + ocol];
                else if (p == 3) v = ThL[(cF + f) * cO + ocol];
                else             v = ThL[(2 * cF + f) * cO + ocol];
            }
            bfr[s][j] = (_Float16)v;
        }
    }

    // ---- MFMA: 9 m-tiles x 3 k-steps; A-frags loaded directly as float4 ----
    f32x4 acc[9];
#pragma unroll
    for (int mt = 0; mt < 9; ++mt) acc[mt] = (f32x4){0.f, 0.f, 0.f, 0.f};
#pragma unroll
    for (int s = 0; s < 3; ++s) {
        const int cdw = 4 * lg + 16 * s;   // k-dword base; frag = dwords cdw..cdw+3
        const bool kpad = (s == 2 && lg >= 2);  // k-cols 80..95: B is zero; don't load
        u32x4 a4[9];
#pragma unroll
        for (int mt = 0; mt < 9; ++mt) {
            int j = 4 * mt + jlr;
            if (kpad || (mt == 8 && j >= cN)) {
                a4[mt] = (u32x4){0u, 0u, 0u, 0u};
            } else {
                a4[mt] = *(const u32x4*)&Hst[hidx(b, t4, j, ttl, cdw)];
            }
        }
#pragma unroll
        for (int mt = 0; mt < 9; ++mt) {
            f16x8 a = __builtin_bit_cast(f16x8, a4[mt]);
            acc[mt] = __builtin_amdgcn_mfma_f32_16x16x32_f16(a, bfr[s], acc[mt], 0, 0, 0);
        }
    }

    __syncthreads();  // ALL waves' staging reads complete before ANY store

    // ---- stores: acc[mt] = out[j=4mt+lg, ocol, t0..t0+3] -> one float4 ----
#pragma unroll
    for (int mt = 0; mt < 9; ++mt) {
        int j = 4 * mt + lg;
        if (j < cN) {
            float4 v;
            v.x = fmaxf(acc[mt][0], 0.f);
            v.y = fmaxf(acc[mt][1], 0.f);
            v.z = fmaxf(acc[mt][2], 0.f);
            v.w = fmaxf(acc[mt][3], 0.f);
            *(float4*)&out[(((size_t)b * cN + j) * cO + ocol) * cT + t0] = v;
        }
    }
}

extern "C" void kernel_launch(void* const* d_in, const int* in_sizes, int n_in,
                              void* d_out, int out_size, void* d_ws, size_t ws_size,
                              hipStream_t stream) {
    const float* x    = (const float*)d_in[0];
    const float* st   = (const float*)d_in[1];
    const float* pos  = (const float*)d_in[2];
    const float* dist = (const float*)d_in[3];
    const float* Th   = (const float*)d_in[4];
    const float* ThL  = (const float*)d_in[5];
    float* out = (float*)d_out;
    float* att = (float*)d_ws;                 // 888 KB fp32 (proven ws usage)
    unsigned* Hst = (unsigned*)d_out;          // H staged inside out, race-free layout

    att_softmax_k<<<(cB * cK * cN + 255) / 256, 256, 0, stream>>>(st, att);
    cheb_h_k<<<cB * cT, 256, 0, stream>>>(x, att, pos, dist, Hst);
    proj_k<<<cB * T4, 256, 0, stream>>>(Hst, Th, ThL, out);
}

// Round 22
// 85.084 us; speedup vs baseline: 1.1412x; 1.1412x over previous
//
#include <hip/hip_runtime.h>
#include <cstddef>

namespace {
constexpr int cB = 64, cN = 34, cF = 16, cT = 96, cK = 3, cO = 64;
constexpr int LPS = 40;   // u16 pitch (80B rows); cols 34..39 zero k-pad
constexpr int BHP = 88;   // kernel-B H pitch (176B rows: 16B-aligned, 2-way-free)
constexpr int T4 = cT / 4;
constexpr float cEPS = 1e-8f;

typedef __attribute__((ext_vector_type(8))) _Float16 f16x8;
typedef __attribute__((ext_vector_type(8))) short   s16x8;
typedef __attribute__((ext_vector_type(4))) float   f32x4;

__device__ inline unsigned short f2h(float v) {
    _Float16 h = (_Float16)v;
    return __builtin_bit_cast(unsigned short, h);
}
__device__ inline float h2f(unsigned short u) {
    return (float)__builtin_bit_cast(_Float16, u);
}

// H staging dword address, interleaved inside d_out. s = tt*40 + c, s < 160.
// Slots of tile (b,t4) live only in out[:, o<40, 4*t4..4*t4+3] — exactly the
// region block (b,t4) of proj_k later overwrites: race-free by construction.
__device__ inline size_t hidx(int b, int t4, int j, int tt, int c) {
    int s = tt * 40 + c;
    return (((size_t)b * cN + j) * cO + (s >> 2)) * cT + 4 * t4 + (s & 3);
}
}

// ---------------- softmax over axis=2 (i) of st_attention (B,K,N,N) ----------------
__global__ __launch_bounds__(256) void att_softmax_k(const float* __restrict__ st,
                                                     float* __restrict__ att) {
    int idx = blockIdx.x * blockDim.x + threadIdx.x;
    if (idx >= cB * cK * cN) return;
    int j = idx % cN;
    int bk = idx / cN;
    const float* base = st + (size_t)bk * cN * cN + j;
    float v[cN];
    float m = -3.402823466e38f;
#pragma unroll
    for (int i = 0; i < cN; ++i) { v[i] = base[(size_t)i * cN]; m = fmaxf(m, v[i]); }
    float s = 0.f;
#pragma unroll
    for (int i = 0; i < cN; ++i) { v[i] = __expf(v[i] - m); s += v[i]; }
    float inv = 1.f / s;
    float* ob = att + (size_t)bk * cN * cN + j;
#pragma unroll
    for (int i = 0; i < cN; ++i) ob[(size_t)i * cN] = v[i] * inv;
}

// ---------------- kernel A: one block per (b,t); H(34x80 fp16) -> staged in out ----------------
// r15 structure (proven 85.1us): A gets its own buffer (s_Abuf) which later
// becomes the M2T/M4T home -> no stash, no pad re-zeroing in P3, b5 deleted
// (P5 writes dead A space right after P4). 5 interior barriers.
// r17 lesson: do NOT wrap this body in a t-loop — the loop demotes the MFMA
// accumulators to scratch (30x FETCH/WRITE explosion).
__global__ __launch_bounds__(256, 8) void cheb_h_k(
    const float* __restrict__ x,      // (B,N,F,T)
    const float* __restrict__ att,    // (B,K,N,N) softmaxed
    const float* __restrict__ pos,    // (N,2)
    const float* __restrict__ dist,   // (N,N)
    unsigned* __restrict__ Hst)       // = (unsigned*)out, staging slots
{
    // Declaration order matters (A-frag row-overrun reads up to ~1120B past an
    // array must land in allocated LDS): Abuf(w3 M4T overruns into L1), L2->M1T,
    // M1T->M3T, M3T->gsT (1280B >= 1118B needed).
    __shared__ __align__(16) unsigned short s_Abuf[2 * cN * LPS]; // A fp32 ovl; M2T rows0..33, M4T rows34..67
    __shared__ __align__(16) unsigned short s_L1[cN * LPS];   // L1 (pads stay init-zero)
    __shared__ __align__(16) unsigned short s_L2[cN * LPS];   // L2
    __shared__ __align__(16) unsigned short s_M1T[cN * LPS];  // att1 .* L1, transposed
    __shared__ __align__(16) unsigned short s_M3T[cN * LPS];  // att1 .* L2, transposed
    __shared__ __align__(16) unsigned short s_gsT[cF * LPS];  // gs^T fp16 (single-writer)
    __shared__ float s_d0[cN], s_v1[cN], s_v2[cN], s_p1[cN], s_p2[cN], s_di1[cN], s_di2[cN];

    const int tid = threadIdx.x;
    const int lane = tid & 63;
    const int w = tid >> 6;
    const int lr = lane & 15;
    const int lg = lane >> 4;
    const int kb8 = lg * 8;

    // XCD swizzle (grid 6144, %8==0 -> bijective)
    const unsigned g = blockIdx.x;
    const unsigned lin = (g & 7u) * (cB * cT / 8) + (g >> 3);
    const int b = lin / cT, t = lin % cT;
    const int t4 = t >> 2, tt = t & 3;

    // idx -> (i,j) decomposition, computed once, reused in P2/P3
    int ii[5], jj[5];
#pragma unroll
    for (int e = 0; e < 5; ++e) {
        int idx = tid + 256 * e;
        ii[e] = idx / cN;
        jj[e] = idx - ii[e] * cN;
    }

    // ---- init: zero L/MT arrays (f32x4); stage p-hat/d0/v'/gsT. Abuf NOT zeroed
    //      (A fp32 overlays it; fp16 pads handled in P5). ----
    {
        f32x4 z = (f32x4){0.f, 0.f, 0.f, 0.f};
        for (int i2 = tid; i2 < cN * LPS / 8; i2 += 256) {
            ((f32x4*)s_L1)[i2] = z; ((f32x4*)s_L2)[i2] = z;
            ((f32x4*)s_M1T)[i2] = z; ((f32x4*)s_M3T)[i2] = z;
        }
    }
    if (tid < cN) {
        float px = pos[2 * tid], py = pos[2 * tid + 1];
        float pn = sqrtf(px * px + py * py);
        float r = 1.f / fmaxf(pn, cEPS);
        s_p1[tid] = px * r; s_p2[tid] = py * r;
        s_d0[tid] = att[((size_t)b * cK) * cN * cN + tid * cN + tid];
    } else if (tid >= 64 && tid < 64 + cN) {
        int n = tid - 64;
        float x1 = x[(((size_t)b * cN + n) * cF + 1) * cT + t];
        float x2 = x[(((size_t)b * cN + n) * cF + 2) * cT + t];
        float vn = sqrtf(x1 * x1 + x2 * x2);
        float s = vn / fmaxf(vn, cEPS);
        s_v1[n] = x1 * s; s_v2[n] = x2 * s;
    }
    // single-writer gsT fill: data for n<34, zero pads for n>=34 (race lesson, r8)
    for (int idx = tid; idx < cF * LPS; idx += 256) {
        int f = idx / LPS, n = idx - f * LPS;
        unsigned short v = 0;
        if (n < cN) v = f2h(x[(((size_t)b * cN + n) * cF + f) * cT + t]);
        s_gsT[idx] = v;
    }
    __syncthreads();  // b1

    // ---- P2: adjacency A fp32 (compact 34x34) into s_Abuf ----
    float* Af = (float*)s_Abuf;
#pragma unroll
    for (int e = 0; e < 5; ++e) {
        int idx = tid + 256 * e;
        if (idx < cN * cN) {
            int i = ii[e], m = jj[e];
            float dot = s_v1[i] * s_p1[m] + s_v2[i] * s_p2[m];
            Af[idx] = __fdividef(fmaxf(dot, 0.f), dist[idx]);
        }
    }
    __syncthreads();  // b2

    // ---- P2b: degrees, 2 threads per sum (17 elems each + shfl combine) ----
    if (tid < 136) {
        int s = tid >> 1, half = tid & 1;
        float acc = 0.f;
        if (s < cN) {
            const float* row = Af + s * cN + half * 17;
#pragma unroll
            for (int m = 0; m < 17; ++m) acc += row[m];
        } else {
            int j = s - cN;
            const float* col = Af + half * 17 * cN + j;
#pragma unroll
            for (int i = 0; i < 17; ++i) acc += col[i * cN];
        }
        float tot = acc + __shfl_xor(acc, 1, 64);
        if (half == 0) {
            float d = (tot > 0.f) ? rsqrtf(fmaxf(tot, 1e-12f)) : 0.f;
            if (s < cN) s_di1[s] = d; else s_di2[s - cN] = d;
        }
    }
    __syncthreads();  // b3 (di done; A stays readable — no stash needed)

    // ---- P3: L1/L2 fp16 (pads untouched = init zeros), M1T/M3T = att1.*L^T ----
    const float* att1 = att + ((size_t)b * cK + 1) * cN * cN;
    const float* att2 = att + ((size_t)b * cK + 2) * cN * cN;
#pragma unroll
    for (int e = 0; e < 5; ++e) {
        int idx = tid + 256 * e;
        if (idx < cN * cN) {
            int i = ii[e], j = jj[e];
            float diag = (i == j) ? 1.f : 0.f;
            float aij = Af[idx];
            float aji = Af[j * cN + i];
            float l1 = diag - s_di1[i] * aij * s_di1[j];
            float l2 = diag - s_di2[i] * aji * s_di2[j];
            int rm = i * LPS + j, tm = j * LPS + i;
            s_L1[rm] = f2h(l1);
            s_L2[rm] = f2h(l2);
            float a1 = att1[idx];
            s_M1T[tm] = f2h(a1 * l1);
            s_M3T[tm] = f2h(a1 * l2);
        }
    }
    __syncthreads();  // b4 (A reads done; L/MT ready)

    // ---- P4: C = L@L fp16 MFMA; ks1: A at fixed col 32 (all lanes), B zeroed
    //      except lg==0 k=32,33 -> lg>0 k-slices contribute A*0 = 0 ----
    const unsigned short* Ah = (w < 2) ? s_L1 : s_L2;
    const int nnt = (w & 1) ? 1 : 2;
    const int ntb0 = (w & 1) ? 32 : 0;
    f32x4 cd0[3], cd1[3];
#pragma unroll
    for (int mt = 0; mt < 3; ++mt) {
        cd0[mt] = (f32x4){0.f, 0.f, 0.f, 0.f};
        cd1[mt] = (f32x4){0.f, 0.f, 0.f, 0.f};
    }
#pragma unroll
    for (int ks = 0; ks < 2; ++ks) {
        f16x8 fah[3];
#pragma unroll
        for (int mt = 0; mt < 3; ++mt) {
            int off = (ks == 0) ? kb8 : 32;
            fah[mt] = *(const f16x8*)&Ah[(mt * 16 + lr) * LPS + off];
        }
#pragma unroll
        for (int un = 0; un < 2; ++un) {
            if (un == 1 && nnt < 2) break;
            int col = ntb0 + un * 16 + lr;
            s16x8 fbb;
            if (ks == 0) {
                // kk = kb8+e2 <= 31 < 34: always valid
#pragma unroll
                for (int e2 = 0; e2 < 8; ++e2)
                    fbb[e2] = (short)Ah[(kb8 + e2) * LPS + col];
            } else {
                // kk = 32+kb8+e2: valid only lg==0 && e2<2; rest zero
#pragma unroll
                for (int e2 = 0; e2 < 8; ++e2) fbb[e2] = 0;
                if (lg == 0) {
                    fbb[0] = (short)Ah[32 * LPS + col];
                    fbb[1] = (short)Ah[33 * LPS + col];
                }
            }
            f16x8 fb = __builtin_bit_cast(f16x8, fbb);
#pragma unroll
            for (int mt = 0; mt < 3; ++mt) {
                f32x4 acc = un ? cd1[mt] : cd0[mt];
                acc = __builtin_amdgcn_mfma_f32_16x16x32_f16(fah[mt], fb, acc, 0, 0, 0);
                if (un) cd1[mt] = acc; else cd0[mt] = acc;
            }
        }
    }
    // NO barrier: P5 writes s_Abuf (dead A space), not the L arrays other
    // waves may still be reading in P4. Register-fed from this wave's cd.

    // ---- P5: M2T = att2 .* (2C1 - I) -> Abuf rows 0..33; M4T -> rows 34..67.
    //      Also zero fp16 pad cols 34..39 (A-garbage could be NaN-as-fp16). ----
    {
        unsigned* Md32 = (unsigned*)s_Abuf + ((w < 2) ? 0 : (cN * LPS / 2));
#pragma unroll
        for (int un = 0; un < 2; ++un) {
            if (un == 1 && nnt < 2) break;
            int jb = ntb0 + un * 16 + lr;
            if (jb < cN) {
#pragma unroll
                for (int mt = 0; mt < 3; ++mt) {
#pragma unroll
                    for (int h = 0; h < 2; ++h) {
                        int ia = mt * 16 + lg * 4 + 2 * h;   // even; ia+1 <= 33 when ia < 34
                        if (ia < cN) {
                            float dva = h ? (un ? cd1[mt][2] : cd0[mt][2])
                                          : (un ? cd1[mt][0] : cd0[mt][0]);
                            float dvb = h ? (un ? cd1[mt][3] : cd0[mt][3])
                                          : (un ? cd1[mt][1] : cd0[mt][1]);
                            float cva = 2.f * dva - ((ia == jb) ? 1.f : 0.f);
                            float cvb = 2.f * dvb - ((ia + 1 == jb) ? 1.f : 0.f);
                            unsigned lo = f2h(att2[ia * cN + jb] * cva);
                            unsigned hi = f2h(att2[(ia + 1) * cN + jb] * cvb);
                            Md32[jb * (LPS / 2) + (ia >> 1)] = lo | (hi << 16);
                        }
                    }
                }
                // pad cols 34..39 of row jb -> true zero (3 dwords)
                Md32[jb * (LPS / 2) + 17] = 0u;
                Md32[jb * (LPS / 2) + 18] = 0u;
                Md32[jb * (LPS / 2) + 19] = 0u;
            }
        }
    }
    __syncthreads();  // b5 (M2T/M4T ready for cross-wave P6 reads)

    // ---- P6: H_p = M_p^T @ gs (wave w -> p=w+1); direct global stores ----
    {
        const unsigned short* Ap = (w == 0) ? s_M1T : (w == 1) ? s_Abuf
                                 : (w == 2) ? s_M3T : (s_Abuf + cN * LPS);
        f32x4 hd[3];
#pragma unroll
        for (int mt = 0; mt < 3; ++mt) hd[mt] = (f32x4){0.f, 0.f, 0.f, 0.f};
#pragma unroll
        for (int ks = 0; ks < 2; ++ks) {
            f16x8 fb;
            if (ks == 0) {
                fb = *(const f16x8*)&s_gsT[lr * LPS + kb8];
            } else {
                // B zero except lg==0 (k=32,33 + zero pads 34..39)
                s16x8 z = {0, 0, 0, 0, 0, 0, 0, 0};
                if (lg == 0) z = *(const s16x8*)&s_gsT[lr * LPS + 32];
                fb = __builtin_bit_cast(f16x8, z);
            }
#pragma unroll
            for (int mt = 0; mt < 3; ++mt) {
                int off = (ks == 0) ? kb8 : 32;   // ks1: all lanes col 32 (B zeroed)
                f16x8 fa = *(const f16x8*)&Ap[(mt * 16 + lr) * LPS + off];
                hd[mt] = __builtin_amdgcn_mfma_f32_16x16x32_f16(fa, fb, hd[mt], 0, 0, 0);
            }
        }
        // p0 diag block (H cols 0..15 = dwords 0..7), all threads
        for (int idx = tid; idx < cN * 8; idx += 256) {
            int j = idx >> 3, c = idx & 7;
            float d = s_d0[j];
            unsigned lo = f2h(d * h2f(s_gsT[(2 * c) * LPS + j]));
            unsigned hi = f2h(d * h2f(s_gsT[(2 * c + 1) * LPS + j]));
            Hst[hidx(b, t4, j, tt, c)] = lo | (hi << 16);
        }
        // pack lane pairs (cols pc+lr, pc+lr^1) -> one dword; split stores by r
        const int pc = 16 * (w + 1);
        const int cdw = (pc >> 1) + (lr >> 1);
#pragma unroll
        for (int mt = 0; mt < 3; ++mt) {
#pragma unroll
            for (int r = 0; r < 4; ++r) {
                int j = mt * 16 + lg * 4 + r;
                unsigned mine = (unsigned)f2h(hd[mt][r]);
                unsigned other = __shfl_xor(mine, 1, 64);
                unsigned dword = (lr & 1) ? ((other & 0xffffu) | (mine << 16))
                                          : (mine | (other << 16));
                bool mystore = ((lr & 1) == 0) ? (r < 2) : (r >= 2);
                if (mystore && j < cN)
                    Hst[hidx(b, t4, j, tt, cdw)] = dword;
            }
        }
    }
}

// ---------------- kernel B: one block per (b,t4); out = relu(H @ Thcat) ----------------
// Reads its own staging slots into LDS (barrier), then overwrites exactly those
// t-columns with final output -> no cross-block hazard by construction.
// r21 lesson: LDS-free variant is SLOWER (4 waves redundantly load identical
// A-fragments from global, scattered 16B loads) — keep the shared LDS bounce.
__global__ __launch_bounds__(256, 4) void proj_k(
    const unsigned* __restrict__ Hst,   // staging view of out
    const float* __restrict__ Th,       // (K,F,O)
    const float* __restrict__ ThL,      // (K,F,O)
    float* __restrict__ out)            // (B,N,O,T)
{
    __shared__ __align__(16) unsigned short s_H[144 * BHP + 16];  // +16: A-frag overrun pad

    const int tid = threadIdx.x;
    const int lane = tid & 63;
    const int w = tid >> 6;
    const int lr = lane & 15;
    const int lg = lane >> 4;
    const int kb8 = lg * 8;
    const int ocol = w * 16 + lr;

    const unsigned g = blockIdx.x;
    const unsigned lin = (g & 7u) * (cB * T4 / 8) + (g >> 3);
    const int b = lin / T4, t4 = lin % T4;
    const int t0 = t4 * 4;

    // ---- Theta B-fragments fp16 (c = p*16+f; p0 = Th0+ThL0 merged) ----
    f16x8 bfr[3];
#pragma unroll
    for (int s = 0; s < 3; ++s) {
#pragma unroll
        for (int j = 0; j < 8; ++j) {
            int cc = 32 * s + kb8 + j;
            float v = 0.f;
            if (cc < 80) {
                int p = cc >> 4, f = cc & 15;
                if (p == 0)      v = Th[f * cO + ocol] + ThL[f * cO + ocol];
                else if (p == 1) v = Th[(cF + f) * cO + ocol];
                else if (p == 2) v = Th[(2 * cF + f) * cO + ocol];
                else if (p == 3) v = ThL[(cF + f) * cO + ocol];
                else             v = ThL[(2 * cF + f) * cO + ocol];
            }
            bfr[s][j] = (_Float16)v;
        }
    }

    // ---- load H tile from staging slots into pitch-BHP LDS; pads zero ----
    {
        unsigned* dst = (unsigned*)s_H;
        for (int i2 = tid; i2 < 144 * (BHP / 2); i2 += 256) {
            int r = i2 / (BHP / 2), c = i2 - r * (BHP / 2);
            unsigned v = 0u;
            if (r < 136 && c < 40) {
                v = Hst[hidx(b, t4, r >> 2, r & 3, c)];
            }
            dst[i2] = v;
        }
    }
    __syncthreads();

    // ---- MFMA: 9 m-tiles x 3 k-steps per wave ----
    f32x4 acc[9];
#pragma unroll
    for (int mt = 0; mt < 9; ++mt) acc[mt] = (f32x4){0.f, 0.f, 0.f, 0.f};
#pragma unroll
    for (int s = 0; s < 3; ++s) {
#pragma unroll
        for (int mt = 0; mt < 9; ++mt) {
            f16x8 a = *(const f16x8*)&s_H[(mt * 16 + lr) * BHP + kb8 + 32 * s];
            acc[mt] = __builtin_amdgcn_mfma_f32_16x16x32_f16(a, bfr[s], acc[mt], 0, 0, 0);
        }
    }

    // ---- stores: acc[mt] = out[j=4mt+lg, ocol, t0..t0+3] -> one float4 ----
#pragma unroll
    for (int mt = 0; mt < 9; ++mt) {
        int j = 4 * mt + lg;
        if (j < cN) {
            float4 v;
            v.x = fmaxf(acc[mt][0], 0.f);
            v.y = fmaxf(acc[mt][1], 0.f);
            v.z = fmaxf(acc[mt][2], 0.f);
            v.w = fmaxf(acc[mt][3], 0.f);
            *(float4*)&out[(((size_t)b * cN + j) * cO + ocol) * cT + t0] = v;
        }
    }
}

extern "C" void kernel_launch(void* const* d_in, const int* in_sizes, int n_in,
                              void* d_out, int out_size, void* d_ws, size_t ws_size,
                              hipStream_t stream) {
    const float* x    = (const float*)d_in[0];
    const float* st   = (const float*)d_in[1];
    const float* pos  = (const float*)d_in[2];
    const float* dist = (const float*)d_in[3];
    const float* Th   = (const float*)d_in[4];
    const float* ThL  = (const float*)d_in[5];
    float* out = (float*)d_out;
    float* att = (float*)d_ws;                 // 888 KB fp32 (proven ws usage)
    unsigned* Hst = (unsigned*)d_out;          // H staged inside out, race-free layout

    att_softmax_k<<<(cB * cK * cN + 255) / 256, 256, 0, stream>>>(st, att);
    cheb_h_k<<<cB * cT, 256, 0, stream>>>(x, att, pos, dist, Hst);
    proj_k<<<cB * T4, 256, 0, stream>>>(Hst, Th, ThL, out);
}